// Round 3
// baseline (9121.776 us; speedup 1.0000x reference)
//
#include <hip/hip_runtime.h>
#include <hip/hip_bf16.h>
#include <stdint.h>

// Problem dims
#define B_  64
#define T_  1024
#define F_  512
#define U_  1024
#define G4_ 4096
#define C_  1000
#define CT_ 16          // timesteps per xz chunk
#define NCH_ (T_ / CT_) // 64 chunks

typedef __bf16 bf16x8 __attribute__((ext_vector_type(8)));
typedef float  f32x4  __attribute__((ext_vector_type(4)));

static __device__ __forceinline__ unsigned short f2bf(float f) {
  __hip_bfloat16 h = __float2bfloat16(f);
  return __builtin_bit_cast(unsigned short, h);
}
static __device__ __forceinline__ float bf2f(unsigned short u) {
  return __uint_as_float(((unsigned)u) << 16);
}
static __device__ __forceinline__ float sig1(float x) {
  return 1.f / (1.f + __expf(-x));
}
static __device__ __forceinline__ float tanh1(float x) {
  float ax = fabsf(x);
  float e  = __expf(2.f * ax);
  float r  = (e - 1.f) / (e + 1.f);
  r = (ax > 15.f) ? 1.f : r;
  return copysignf(r, x);
}

static __device__ __forceinline__ void gload_lds16(const void* g, void* l) {
  __builtin_amdgcn_global_load_lds(
      (const __attribute__((address_space(1))) unsigned int*)g,
      (__attribute__((address_space(3))) unsigned int*)l, 16, 0, 0);
}

// ---------------- K1a/b: f32 [R][C] -> bf16 [C][R] transpose ----------------
__global__ __launch_bounds__(256) void k_transpose_bf16(
    const float* __restrict__ in, unsigned short* __restrict__ out, int R, int C) {
  __shared__ float tile[64][65];
  int c0 = blockIdx.x * 64, r0 = blockIdx.y * 64;
  int tid = threadIdx.x;
  int tr = tid >> 4, tc4 = (tid & 15) * 4;
#pragma unroll
  for (int rr = 0; rr < 64; rr += 16) {
    float4 v = *(const float4*)&in[(size_t)(r0 + rr + tr) * C + c0 + tc4];
    tile[rr + tr][tc4 + 0] = v.x;
    tile[rr + tr][tc4 + 1] = v.y;
    tile[rr + tr][tc4 + 2] = v.z;
    tile[rr + tr][tc4 + 3] = v.w;
  }
  __syncthreads();
#pragma unroll
  for (int cc = 0; cc < 64; cc += 16) {
    int c = cc + tr;   // output row (original col)
    int r = tc4;       // original row base
    ushort4 o;
    o.x = f2bf(tile[r + 0][c]);
    o.y = f2bf(tile[r + 1][c]);
    o.z = f2bf(tile[r + 2][c]);
    o.w = f2bf(tile[r + 3][c]);
    *(ushort4*)&out[(size_t)(c0 + c) * R + r0 + r] = o;
  }
}

// ---------------- K1c: x [b][t][f] f32 -> xbf chunk [t'][b][f] bf16 ---------
__global__ __launch_bounds__(256) void k_xbf_chunk(
    const float* __restrict__ x, unsigned short* __restrict__ xbfc, int t0) {
  int row = blockIdx.x;           // t'*64 + b, t' in [0,CT_)
  int tp = row >> 6, b = row & 63;
  int tid = threadIdx.x;
  float2 v = *(const float2*)&x[((size_t)b * T_ + t0 + tp) * F_ + tid * 2];
  ushort2 o;
  o.x = f2bf(v.x);
  o.y = f2bf(v.y);
  *(ushort2*)&xbfc[(size_t)row * F_ + tid * 2] = o;
}

// ---------------- K2: xz chunk = xbfc @ Wk (M=1024, N=4096, K=512) ----------
// Output layout: frag dump  XZC[t'(16)][g(4)][nt(256)][lane(64)][j(4)]  bf16
__global__ __launch_bounds__(256, 2) void k_gemm_xz(
    const unsigned short* __restrict__ xbf,   // [CT_*64][512]
    const unsigned short* __restrict__ wkt,   // [4096][512]
    unsigned short* __restrict__ xz) {
  __shared__ unsigned short As[2][128 * 64];
  __shared__ unsigned short Bs[2][128 * 64];
  int bid = blockIdx.x;
  int bm = bid >> 5;   // 0..7
  int bn = bid & 31;   // 0..31
  int m0 = bm * 128, n0 = bn * 128;
  int tid = threadIdx.x;
  int w = tid >> 6, l = tid & 63;
  int wr = w >> 1, wc = w & 1;
  int r8 = l >> 3, ch = l & 7;

  f32x4 acc[4][4];
#pragma unroll
  for (int i = 0; i < 4; ++i)
#pragma unroll
    for (int j = 0; j < 4; ++j) acc[i][j] = f32x4{0.f, 0.f, 0.f, 0.f};

  auto stage = [&](int buf, int kt) {
#pragma unroll
    for (int i = 0; i < 4; ++i) {
      int row = w * 32 + i * 8 + r8;
      int chs = ch ^ (row & 7);  // source pre-swizzle -> linear LDS holds swizzled chunks
      gload_lds16((const char*)xbf + (size_t)(m0 + row) * 1024 + kt * 128 + chs * 16,
                  (char*)&As[buf][0] + (size_t)(w * 32 + i * 8) * 128);
      gload_lds16((const char*)wkt + (size_t)(n0 + row) * 1024 + kt * 128 + chs * 16,
                  (char*)&Bs[buf][0] + (size_t)(w * 32 + i * 8) * 128);
    }
  };

  stage(0, 0);
  __syncthreads();
  for (int kt = 0; kt < 8; ++kt) {
    int cur = kt & 1;
    if (kt < 7) stage(cur ^ 1, kt + 1);
    bf16x8 af[4][2], bfr[4][2];
#pragma unroll
    for (int ks = 0; ks < 2; ++ks) {
#pragma unroll
      for (int mi = 0; mi < 4; ++mi) {
        int rowa = wr * 64 + mi * 16 + (l & 15);
        int cha = (ks * 4 + (l >> 4)) ^ (rowa & 7);
        af[mi][ks] = *(const bf16x8*)((const char*)&As[cur][0] + rowa * 128 + cha * 16);
        int rowb = wc * 64 + mi * 16 + (l & 15);
        int chb = (ks * 4 + (l >> 4)) ^ (rowb & 7);
        bfr[mi][ks] = *(const bf16x8*)((const char*)&Bs[cur][0] + rowb * 128 + chb * 16);
      }
    }
#pragma unroll
    for (int mi = 0; mi < 4; ++mi)
#pragma unroll
      for (int ni = 0; ni < 4; ++ni)
#pragma unroll
        for (int ks = 0; ks < 2; ++ks)
          acc[mi][ni] = __builtin_amdgcn_mfma_f32_16x16x32_bf16(
              af[mi][ks], bfr[ni][ks], acc[mi][ni], 0, 0, 0);
    __syncthreads();
  }

  // Epilogue: raw D-frag dump. t' = 2*bm + wr, group g = mi, nt = bn*8+wc*4+ni.
  int tt = 2 * bm + wr;
#pragma unroll
  for (int mi = 0; mi < 4; ++mi) {
#pragma unroll
    for (int ni = 0; ni < 4; ++ni) {
      int nt = bn * 8 + wc * 4 + ni;
      ushort4 o;
      o.x = f2bf(acc[mi][ni][0]);
      o.y = f2bf(acc[mi][ni][1]);
      o.z = f2bf(acc[mi][ni][2]);
      o.w = f2bf(acc[mi][ni][3]);
      *(ushort4*)&xz[((((size_t)tt * 4 + mi) * 256 + nt) * 64 + l) * 4] = o;
    }
  }
}

// ---------------- K3: one LSTM timestep ----------------
// grid = 256 blocks: g = blockIdx>>6 (batch group of 16), wblk = blockIdx&63 (u block of 16)
// 4 waves split K=1024 into quarters; LDS reduce; wave w4 owns gate w4.
__global__ __launch_bounds__(256) void k_step(
    const unsigned short* __restrict__ hcur,   // [64][1024] bf16
    unsigned short* __restrict__ hnxt,
    const unsigned short* __restrict__ wrt,    // [4096][1024] bf16
    const unsigned short* __restrict__ xz,     // chunk slot base
    const float* __restrict__ bias,            // [4096]
    float* __restrict__ cbuf,                  // [64][1024] f32
    float* __restrict__ hfin,                  // [64][1024] f32
    int tloc, int last) {
  __shared__ f32x4 pbuf[4][4][64];   // [wave][gate-tile][lane]
  __shared__ f32x4 gbuf[4][64];      // [gate][lane]
  int g = blockIdx.x >> 6, wblk = blockIdx.x & 63;
  int tid = threadIdx.x;
  int w4 = tid >> 6, l = tid & 63;
  int l15 = l & 15, lk = (l >> 4) * 8;
  int kb = w4 * 256;

  // hoisted loads for the reduce phase
  ushort4 xv = *(const ushort4*)&xz[((((size_t)tloc * 4 + g) * 256 + (w4 * 64 + wblk)) * 64 + l) * 4];
  float bv = bias[w4 * 1024 + wblk * 16 + l15];

  const unsigned short* ap = hcur + (size_t)(g * 16 + l15) * 1024 + kb + lk;
  const unsigned short* bp = wrt + (size_t)(wblk * 16 + l15) * 1024 + kb + lk;

  f32x4 a0 = f32x4{0.f,0.f,0.f,0.f}, a1 = a0, a2 = a0, a3 = a0;
#pragma unroll
  for (int ks = 0; ks < 8; ++ks) {
    bf16x8 a  = *(const bf16x8*)(ap + ks * 32);
    bf16x8 b0 = *(const bf16x8*)(bp + 0 * 1048576 + ks * 32);
    bf16x8 b1 = *(const bf16x8*)(bp + 1 * 1048576 + ks * 32);
    bf16x8 b2 = *(const bf16x8*)(bp + 2 * 1048576 + ks * 32);
    bf16x8 b3 = *(const bf16x8*)(bp + 3 * 1048576 + ks * 32);
    a0 = __builtin_amdgcn_mfma_f32_16x16x32_bf16(a, b0, a0, 0, 0, 0);
    a1 = __builtin_amdgcn_mfma_f32_16x16x32_bf16(a, b1, a1, 0, 0, 0);
    a2 = __builtin_amdgcn_mfma_f32_16x16x32_bf16(a, b2, a2, 0, 0, 0);
    a3 = __builtin_amdgcn_mfma_f32_16x16x32_bf16(a, b3, a3, 0, 0, 0);
  }
  pbuf[w4][0][l] = a0;
  pbuf[w4][1][l] = a1;
  pbuf[w4][2][l] = a2;
  pbuf[w4][3][l] = a3;
  __syncthreads();

  f32x4 z = pbuf[0][w4][l];
  z += pbuf[1][w4][l];
  z += pbuf[2][w4][l];
  z += pbuf[3][w4][l];
  z[0] += bf2f(xv.x) + bv;
  z[1] += bf2f(xv.y) + bv;
  z[2] += bf2f(xv.z) + bv;
  z[3] += bf2f(xv.w) + bv;
  if (w4 == 2) {
#pragma unroll
    for (int j = 0; j < 4; ++j) z[j] = tanh1(z[j]);
  } else {
#pragma unroll
    for (int j = 0; j < 4; ++j) z[j] = sig1(z[j]);
  }
  gbuf[w4][l] = z;
  __syncthreads();

  // c/h update: thread tid -> (m = tid>>4 sample-local, u = tid&15)
  int m = tid >> 4, u = tid & 15;
  int l2 = ((m >> 2) << 4) | u, j2 = m & 3;
  float iv = gbuf[0][l2][j2];
  float fv = gbuf[1][l2][j2];
  float gv = gbuf[2][l2][j2];
  float ov = gbuf[3][l2][j2];
  size_t cidx = (size_t)(g * 16 + m) * 1024 + wblk * 16 + u;
  float c = cbuf[cidx];
  c = fv * c + iv * gv;
  cbuf[cidx] = c;
  float h = ov * tanh1(c);
  hnxt[cidx] = f2bf(h);
  if (last) hfin[cidx] = h;
}

// ---------------- K4: logits = h@Wd + bd, softmax ----------------
__global__ __launch_bounds__(256) void k_final(
    const float* __restrict__ hfin, const float* __restrict__ Wd,
    const float* __restrict__ bd, float* __restrict__ out) {
  __shared__ float hrow[1024];
  __shared__ float red[256];
  int b = blockIdx.x, tid = threadIdx.x;
  float4 hv = *(const float4*)&hfin[(size_t)b * 1024 + tid * 4];
  hrow[tid * 4 + 0] = hv.x;
  hrow[tid * 4 + 1] = hv.y;
  hrow[tid * 4 + 2] = hv.z;
  hrow[tid * 4 + 3] = hv.w;
  __syncthreads();
  float vals[4];
#pragma unroll
  for (int chn = 0; chn < 4; ++chn) {
    int c = chn * 256 + tid;
    float a = -1e30f;
    if (c < C_) {
      a = bd[c];
#pragma unroll 4
      for (int k = 0; k < 1024; ++k) a += hrow[k] * Wd[k * 1000 + c];
    }
    vals[chn] = a;
  }
  float mx = fmaxf(fmaxf(vals[0], vals[1]), fmaxf(vals[2], vals[3]));
  red[tid] = mx;
  __syncthreads();
  for (int s = 128; s > 0; s >>= 1) {
    if (tid < s) red[tid] = fmaxf(red[tid], red[tid + s]);
    __syncthreads();
  }
  float M = red[0];
  __syncthreads();
  float ex[4];
  float sm = 0.f;
#pragma unroll
  for (int chn = 0; chn < 4; ++chn) {
    int c = chn * 256 + tid;
    ex[chn] = (c < C_) ? __expf(vals[chn] - M) : 0.f;
    sm += ex[chn];
  }
  red[tid] = sm;
  __syncthreads();
  for (int s = 128; s > 0; s >>= 1) {
    if (tid < s) red[tid] += red[tid + s];
    __syncthreads();
  }
  float inv = 1.f / red[0];
#pragma unroll
  for (int chn = 0; chn < 4; ++chn) {
    int c = chn * 256 + tid;
    if (c < C_) out[(size_t)b * C_ + c] = ex[chn] * inv;
  }
}

// ---------------- launch ----------------
extern "C" void kernel_launch(void* const* d_in, const int* in_sizes, int n_in,
                              void* d_out, int out_size, void* d_ws, size_t ws_size,
                              hipStream_t stream) {
  const float* x    = (const float*)d_in[0];
  const float* Wk   = (const float*)d_in[1];
  const float* Wr   = (const float*)d_in[2];
  const float* bias = (const float*)d_in[3];
  const float* Wd   = (const float*)d_in[4];
  const float* bd   = (const float*)d_in[5];
  float* out = (float*)d_out;

  // ws layout (bytes); chunked xz: double-buffered CT_=16 timesteps
  const size_t OFF_WKT  = 0;                      // 4096*512*2        = 4,194,304
  const size_t OFF_WRT  = 4194304;                // 4096*1024*2       = 8,388,608
  const size_t OFF_XBFC = 12582912;               // 2*16*64*512*2     = 2,097,152
  const size_t OFF_XZC  = 14680064;               // 2*16*64*4096*2    = 16,777,216
  const size_t OFF_HB   = 31457280;               // 2*65536*2         = 262,144
  const size_t OFF_CB   = 31719424;               // 65536*4           = 262,144
  const size_t OFF_HF   = 31981568;               // 65536*4           = 262,144
  const size_t NEED     = 32243712;               // ~30.8 MB

  if (ws_size < NEED) {
    // distinctive failure signature: 0x7F7F7F7F pattern = 3.39e38 in output
    hipMemsetAsync(d_out, 0x7F, (size_t)out_size * sizeof(float), stream);
    return;
  }

  char* ws = (char*)d_ws;
  unsigned short* WKT  = (unsigned short*)(ws + OFF_WKT);
  unsigned short* WRT  = (unsigned short*)(ws + OFF_WRT);
  unsigned short* XBFC = (unsigned short*)(ws + OFF_XBFC);  // 2 slots x 524288 elems
  unsigned short* XZC  = (unsigned short*)(ws + OFF_XZC);   // 2 slots x 4194304 elems
  unsigned short* HB   = (unsigned short*)(ws + OFF_HB);
  float* CB = (float*)(ws + OFF_CB);
  float* HF = (float*)(ws + OFF_HF);

  hipMemsetAsync(HB, 0, 131072, stream);   // h0 = 0 (slot 0 only)
  hipMemsetAsync(CB, 0, 262144, stream);   // c0 = 0

  k_transpose_bf16<<<dim3(G4_ / 64, F_ / 64), 256, 0, stream>>>(Wk, WKT, F_, G4_);
  k_transpose_bf16<<<dim3(G4_ / 64, U_ / 64), 256, 0, stream>>>(Wr, WRT, U_, G4_);

  for (int c = 0; c < NCH_; ++c) {
    int s = c & 1;
    unsigned short* xbfs = XBFC + (size_t)s * (CT_ * 64 * 512);
    unsigned short* xzs  = XZC + (size_t)s * (CT_ * 64 * 4096);
    k_xbf_chunk<<<CT_ * 64, 256, 0, stream>>>(x, xbfs, c * CT_);
    k_gemm_xz<<<8 * 32, 256, 0, stream>>>(xbfs, WKT, xzs);
    for (int tt = 0; tt < CT_; ++tt) {
      int t = c * CT_ + tt;
      const unsigned short* hc = HB + (size_t)(t & 1) * 65536;
      unsigned short* hn = HB + (size_t)((t + 1) & 1) * 65536;
      k_step<<<256, 256, 0, stream>>>(hc, hn, WRT, xzs, bias, CB, HF, tt, t == T_ - 1);
    }
  }

  k_final<<<64, 256, 0, stream>>>(HF, Wd, bd, out);
}